// Round 27
// baseline (119.634 us; speedup 1.0000x reference)
//
#include <hip/hip_runtime.h>
#include <cstdint>

#define BB 128
#define TT 256
#define CC 256
#define HH 8
#define HSZ 32
#define NT (BB*TT)      // 32768 tokens
#define CF (4*CC)       // 1024
#define LN_EPS 1e-5f
#define SCALE 0.0625f   // C^-0.5 = 256^-0.5

typedef __attribute__((ext_vector_type(8))) __bf16 bf16x8;
typedef __attribute__((ext_vector_type(4))) float f32x4;
typedef __attribute__((ext_vector_type(16))) float f32x16;
typedef __attribute__((ext_vector_type(2))) long i64x2;
typedef unsigned short u16;
typedef unsigned int u32;
typedef unsigned char u8;

__device__ __forceinline__ u16 f2bf(float f) {
  u32 u = __float_as_uint(f);
  u32 r = (u + 0x7fffu + ((u >> 16) & 1u)) >> 16;
  return (u16)r;
}
__device__ __forceinline__ u8 f2f8(float f) {
  return (u8)(__builtin_amdgcn_cvt_pk_fp8_f32(f, f, 0, false) & 0xff);
}
// pack 4 floats -> 4 fp8 bytes (byte r = element r)
__device__ __forceinline__ u32 f2f8x4(float a, float b, float c, float d) {
  u32 pk = (u32)__builtin_amdgcn_cvt_pk_fp8_f32(a, b, 0, false);
  return (u32)__builtin_amdgcn_cvt_pk_fp8_f32(c, d, (int)pk, true);
}
// pack 4 floats -> 4 bf16 (packed HW cvt; no builtin on gfx950 -> inline asm)
__device__ __forceinline__ uint2 f2bfx4(float a, float b, float c, float d) {
  uint2 r;
  asm("v_cvt_pk_bf16_f32 %0, %1, %2" : "=v"(r.x) : "v"(a), "v"(b));
  asm("v_cvt_pk_bf16_f32 %0, %1, %2" : "=v"(r.y) : "v"(c), "v"(d));
  return r;
}
// pkrow: 32x32x16-fp8 fragment interleave + swz3 bank swizzle baked into
// GLOBAL layouts (within each 64-B k-group). Staging = PURE LINEAR copy.
__device__ __forceinline__ int swz3i(int r) { return (r ^ (r >> 2)) & 3; }
__device__ __forceinline__ int pkrow(int row, int k) {
  int g = (k >> 4) & 3, h = (k >> 3) & 1, j = k & 7;
  int c = (h << 1) + (g >> 1);
  int cp = c ^ swz3i(row);
  return (k & ~63) + cp * 16 + ((g & 1) << 3) + j;
}

__device__ __forceinline__ void gload16(const void* g, void* l) {
  __builtin_amdgcn_global_load_lds(
      (const __attribute__((address_space(1))) u32*)(uintptr_t)g,
      (__attribute__((address_space(3))) u32*)(u32)(uintptr_t)l,
      16, 0, 0);
}

// counted waits (T4) only in proven steady-state loops; prologues use full
// drains (R11/R12/R13/R16 lesson: reordering or count-discriminating the
// prologue's VMEM groups is unsafe or negative -- family closed).
__device__ __forceinline__ void wait_vm0() {
  asm volatile("s_waitcnt vmcnt(0)" ::: "memory");
  __builtin_amdgcn_sched_barrier(0);
}
__device__ __forceinline__ void wait_vm4() {
  asm volatile("s_waitcnt vmcnt(4)" ::: "memory");
  __builtin_amdgcn_sched_barrier(0);
}
__device__ __forceinline__ void wait_vm8() {
  asm volatile("s_waitcnt vmcnt(8)" ::: "memory");
  __builtin_amdgcn_sched_barrier(0);
}
__device__ __forceinline__ void wait_vm0_lgkm0() {
  asm volatile("s_waitcnt vmcnt(0) lgkmcnt(0)" ::: "memory");
  __builtin_amdgcn_sched_barrier(0);
}
__device__ __forceinline__ void wait_lgkm0() {
  asm volatile("s_waitcnt lgkmcnt(0)" ::: "memory");
  __builtin_amdgcn_sched_barrier(0);
}
__device__ __forceinline__ void sbar() {
  __builtin_amdgcn_s_barrier();
  __builtin_amdgcn_sched_barrier(0);
}

// ---- conv_ln: fused weight transpose-convert (blocks 0..191) + LN1
// (blocks 192..8383).
__global__ __launch_bounds__(256) void conv_ln(
    const float* __restrict__ Wk, const float* __restrict__ Wq,
    const float* __restrict__ Wv, const float* __restrict__ Wp,
    const float* __restrict__ W1, const float* __restrict__ W2,
    u8* __restrict__ WkqvT8, u8* __restrict__ WpT8,
    u8* __restrict__ W1T8, u8* __restrict__ W2T8,
    const float* __restrict__ x, const float* __restrict__ g1,
    const float* __restrict__ be1, u8* __restrict__ hb) {
  __shared__ u8 ldsT[64][68];
  int bid = blockIdx.x, tid = threadIdx.x;
  if (bid >= 192) {
    // ---------------- LN1 ----------------
    int wid = tid >> 6, lane = tid & 63;
    int row = (bid - 192) * 4 + wid;
    const float4 v = reinterpret_cast<const float4*>(x + (size_t)row * CC)[lane];
    float s = v.x + v.y + v.z + v.w;
#pragma unroll
    for (int o = 32; o; o >>= 1) s += __shfl_xor(s, o, 64);
    float mu = s * (1.0f / CC);
    float dx = v.x - mu, dy = v.y - mu, dz = v.z - mu, dw = v.w - mu;
    float ss = dx * dx + dy * dy + dz * dz + dw * dw;
#pragma unroll
    for (int o = 32; o; o >>= 1) ss += __shfl_xor(ss, o, 64);
    float inv = rsqrtf(ss * (1.0f / CC) + LN_EPS);
    const float4 gv = reinterpret_cast<const float4*>(g1)[lane];
    const float4 bv = reinterpret_cast<const float4*>(be1)[lane];
    u32 pk = f2f8x4(gv.x * dx * inv + bv.x, gv.y * dy * inv + bv.y,
                    gv.z * dz * inv + bv.z, gv.w * dw * inv + bv.w);
    *reinterpret_cast<u32*>(hb + (size_t)row * CC + pkrow(row, lane * 4)) = pk;
    return;
  }
  // ---------------- conv_t ----------------
  int n0, k0, K;
  u8* dst;
  int mode;  // 0 = kqv (piecewise head addressing), 1 = linear
  const float* src = nullptr;
  int sk = 0;
  if (bid < 48) {
    mode = 0; n0 = (bid >> 2) * 64; k0 = (bid & 3) * 64; K = 256; dst = WkqvT8;
  } else if (bid < 112) {
    int l = bid - 48;
    mode = 1; n0 = (l >> 2) * 64; k0 = (l & 3) * 64; K = 256; dst = W1T8;
    src = W1; sk = 1024;
  } else if (bid < 176) {
    int l = bid - 112;
    mode = 1; n0 = (l >> 4) * 64; k0 = (l & 15) * 64; K = 1024; dst = W2T8;
    src = W2; sk = 256;
  } else {
    int l = bid - 176;
    mode = 1; n0 = (l >> 2) * 64; k0 = (l & 3) * 64; K = 256; dst = WpT8;
    src = Wp; sk = 256;
  }
  int kr = tid >> 2;               // k-row 0..63
  int nbase = (tid & 3) * 16;      // n-chunk
#pragma unroll
  for (int u = 0; u < 4; ++u) {
    int nl = nbase + u * 4;
    int ng = n0 + nl;
    float4 v;
    if (mode == 0) {
      const float* W = (ng < 256) ? Wk : (ng < 512 ? Wq : Wv);
      int inner = ng & 255;
      v = *reinterpret_cast<const float4*>(
          &W[((inner >> 5) << 13) + (size_t)(k0 + kr) * 32 + (inner & 31)]);
    } else {
      v = *reinterpret_cast<const float4*>(
          &src[(size_t)(k0 + kr) * sk + ng]);
    }
    ldsT[nl + 0][kr] = f2f8(v.x);
    ldsT[nl + 1][kr] = f2f8(v.y);
    ldsT[nl + 2][kr] = f2f8(v.z);
    ldsT[nl + 3][kr] = f2f8(v.w);
  }
  __syncthreads();
  int nl = tid >> 2;
  int nglob = n0 + nl;
  int sz = swz3i(nglob);
  u8* drow = dst + (size_t)nglob * K + k0;
#pragma unroll
  for (int c4 = (tid & 3) * 4; c4 < (tid & 3) * 4 + 4; ++c4) {
    int q = c4 >> 1, s = c4 & 1;
    int kb = q * 8 + s * 4;        // k%8 in {0,4}: contiguous under pkrow
    u32 pk = (u32)ldsT[nl][kb] | ((u32)ldsT[nl][kb + 1] << 8) |
             ((u32)ldsT[nl][kb + 2] << 16) | ((u32)ldsT[nl][kb + 3] << 24);
    int g = (kb >> 4) & 3, h8 = (kb >> 3) & 1;
    int cp = ((h8 << 1) + (g >> 1)) ^ sz;
    *reinterpret_cast<u32*>(drow + cp * 16 + ((g & 1) << 3) + (kb & 7)) = pk;
  }
}

// ---- qkv_fused: QKV GEMM (NB=3 panels). Outputs HEAD-MAJOR:
//   kq8h[h][NT][64B]  (K bytes 0..31, Q bytes 32..63, fp8)
//   v16h[h][NT][32]   (bf16)
__global__ __launch_bounds__(512, 4) void qkv_fused(
    const u8* __restrict__ Asrc, const u8* __restrict__ WT8,
    u8* __restrict__ kq8, u16* __restrict__ v16) {
  __shared__ u8 Bw[4][256][64];   // weight panel [kg][n][64B]  64KB
  int tid = threadIdx.x;
  int w = tid >> 6, lane = tid & 63;
  int l32 = lane & 31, h = lane >> 5;
  int th = w >> 2, fq = w & 3;   // token 32-group, n 64-quarter
  int m0 = blockIdx.x * 64;

#define STAGEP(nb)                                                            \
  {                                                                           \
    _Pragma("unroll") for (int it = 0; it < 8; ++it) {                        \
      int f = it * 512 + tid;                                                 \
      int kg = f >> 10, t = (f >> 2) & 255, c = f & 3;                        \
      gload16(WT8 + (size_t)((nb) * 256 + t) * 256 + kg * 64 + c * 16,        \
              &Bw[0][0][0] + f * 16);                                         \
    }                                                                         \
  }
  // A-fragments -> registers (issued FIRST: oldest in vmcnt FIFO)
  i64x2 aa[4][2];
  {
    int ar = th * 32 + l32;
    int az = swz3i(ar);
#pragma unroll
    for (int kg = 0; kg < 4; ++kg)
#pragma unroll
      for (int p = 0; p < 2; ++p)
        aa[kg][p] = *reinterpret_cast<const i64x2*>(
            Asrc + (size_t)(m0 + ar) * 256 + kg * 64 +
            ((((h << 1) + p) ^ az) << 4));
  }
  STAGEP(0);

#pragma unroll 1
  for (int nb = 0; nb < 3; ++nb) {
    if (nb == 0) wait_vm0(); else wait_vm8();
    sbar();  // panel nb staged & visible to all waves
    f32x16 a1[2] = {};
    __builtin_amdgcn_s_setprio(1);
#pragma unroll
    for (int kg = 0; kg < 4; ++kg) {
#pragma unroll
      for (int p = 0; p < 2; ++p) {
        i64x2 bB[2];
#pragma unroll
        for (int j = 0; j < 2; ++j) {
          int br = fq * 64 + j * 32 + l32, bz = swz3i(br);
          bB[j] = *reinterpret_cast<const i64x2*>(
              &Bw[kg][br][(((h << 1) + p) ^ bz) << 4]);
        }
#pragma unroll
        for (int j = 0; j < 2; ++j) {
          a1[j] = __builtin_amdgcn_mfma_f32_32x32x16_fp8_fp8(
              bB[j][0], aa[kg][p][0], a1[j], 0, 0, 0);
          a1[j] = __builtin_amdgcn_mfma_f32_32x32x16_fp8_fp8(
              bB[j][1], aa[kg][p][1], a1[j], 0, 0, 0);
        }
      }
    }
    __builtin_amdgcn_s_setprio(0);
    sbar();  // all waves done reading Bw
    if (nb < 2) STAGEP(nb + 1);  // prefetch; lands under stores + GEMM
    int m = m0 + th * 32 + l32;
#pragma unroll
    for (int j = 0; j < 2; ++j) {
#pragma unroll
      for (int q = 0; q < 4; ++q) {
        int n = nb * 256 + fq * 64 + j * 32 + q * 8 + h * 4;
        if (n < 256) {
          // K -> fp8, head-major, bytes 0..31 of 64B row
          u32 pk = f2f8x4(a1[j][q * 4 + 0], a1[j][q * 4 + 1],
                          a1[j][q * 4 + 2], a1[j][q * 4 + 3]);
          int hh2 = n >> 5, col = n & 31;
          *reinterpret_cast<u32*>(
              &kq8[((size_t)hh2 * NT + m) * 64 + col]) = pk;
        } else if (n < 512) {
          // Q -> fp8, head-major, bytes 32..63 of 64B row
          u32 pk = f2f8x4(a1[j][q * 4 + 0], a1[j][q * 4 + 1],
                          a1[j][q * 4 + 2], a1[j][q * 4 + 3]);
          int nn = n - 256;
          int hh2 = nn >> 5, col = nn & 31;
          *reinterpret_cast<u32*>(
              &kq8[((size_t)hh2 * NT + m) * 64 + 32 + col]) = pk;
        } else {
          // V -> bf16, head-major (32 u16 = 64B rows)
          u16 pk[4];
#pragma unroll
          for (int r = 0; r < 4; ++r) pk[r] = f2bf(a1[j][q * 4 + r]);
          int nn = n - 512;
          int hh2 = nn >> 5, col = nn & 31;
          *reinterpret_cast<uint2*>(
              &v16[((size_t)hh2 * NT + m) * 32 + col]) =
              *reinterpret_cast<uint2*>(pk);
        }
      }
    }
  }
#undef STAGEP
}

// ---- wp_ffn: R10/R15 structure (proven). o8 HEAD-MAJOR unswizzled:
// o8h[head][NT][32], fragment chunk (kg,p) = 16B at o8h[kg*2+p][m][(lane>>5)*16]
__global__ __launch_bounds__(512, 4) void wp_ffn(
    const u8* __restrict__ o8, const u8* __restrict__ WpT8,
    const float* __restrict__ bp, const float* __restrict__ x,
    const u8* __restrict__ W1T8, const u8* __restrict__ W2T8,
    const float* __restrict__ b1, const float* __restrict__ b2,
    const float* __restrict__ g2, const float* __restrict__ be2,
    u8* __restrict__ hb, float* __restrict__ outp) {
  __shared__ u8 Bw[65536];        // Wp [4][256][64] | W1 @0 [4][128][64] + W2 @32768 [2][256][64]
  __shared__ u8 Ff[2][64][64];    // f exchange       8KB
  __shared__ float b1l[1024];     // b1 staged        4KB
  __shared__ float red[4][64][2]; // LN2 reduce       2KB   (total 78KB)
  int tid = threadIdx.x;
  int w = tid >> 6, lane = tid & 63;
  int l32 = lane & 31, h = lane >> 5;
  int th = w >> 2, fq = w & 3;
  int m0 = blockIdx.x * 64;
  int m = m0 + th * 32 + l32;
  int ar = th * 32 + l32, az = swz3i(ar);

#define STAGE_W1F(nb)                                                         \
  {                                                                           \
    _Pragma("unroll") for (int it = 0; it < 4; ++it) {                        \
      int f = it * 512 + tid;                                                 \
      int kg = f >> 9, t = (f >> 2) & 127, c = f & 3;                         \
      gload16(W1T8 + (size_t)((nb) * 128 + t) * 256 + kg * 64 + c * 16,       \
              Bw + f * 16);                                                   \
    }                                                                         \
  }
#define STAGE_W2F(nb)                                                         \
  {                                                                           \
    _Pragma("unroll") for (int it = 0; it < 4; ++it) {                        \
      int f = it * 512 + tid;                                                 \
      int kg2 = f >> 10, o = (f >> 2) & 255, c = f & 3;                       \
      gload16(W2T8 + (size_t)o * 1024 + (nb) * 128 + kg2 * 64 + c * 16,       \
              Bw + 32768 + f * 16);                                           \
    }                                                                         \
  }

  // ---- phase 0: o8 A-frags (head-major) + Wp panel (64KB) staging ----
  i64x2 aw[4][2];
#pragma unroll
  for (int kg = 0; kg < 4; ++kg)
#pragma unroll
    for (int p = 0; p < 2; ++p)
      aw[kg][p] = *reinterpret_cast<const i64x2*>(
          o8 + ((size_t)(kg * 2 + p) * NT + (m0 + ar)) * 32 + h * 16);
  {
#pragma unroll
    for (int it = 0; it < 8; ++it) {
      int f = it * 512 + tid;
      int kg = f >> 10, t = (f >> 2) & 255, c = f & 3;
      gload16(WpT8 + (size_t)t * 256 + kg * 64 + c * 16, Bw + f * 16);
    }
  }
  wait_vm0();
  sbar();
  // ---- phase 1: Wp GEMM -> xw[2] (becomes the x2 residual, registers) ----
  f32x16 xw[2] = {};
  __builtin_amdgcn_s_setprio(1);
#pragma unroll
  for (int kg = 0; kg < 4; ++kg) {
#pragma unroll
    for (int p = 0; p < 2; ++p) {
      i64x2 bB[2];
#pragma unroll
      for (int j = 0; j < 2; ++j) {
        int br = fq * 64 + j * 32 + l32, bz = swz3i(br);
        bB[j] = *reinterpret_cast<const i64x2*>(
            &Bw[kg * 16384 + br * 64 + ((((h << 1) + p) ^ bz) << 4)]);
      }
#pragma unroll
      for (int j = 0; j < 2; ++j) {
        xw[j] = __builtin_amdgcn_mfma_f32_32x32x16_fp8_fp8(
            bB[j][0], aw[kg][p][0], xw[j], 0, 0, 0);
        xw[j] = __builtin_amdgcn_mfma_f32_32x32x16_fp8_fp8(
            bB[j][1], aw[kg][p][1], xw[j], 0, 0, 0);
      }
    }
  }
  __builtin_amdgcn_s_setprio(0);
  sbar();  // all waves done reading the Wp panel -> Bw reusable
  // ---- phase 2: stage W1(0)/W2(0)/b1 (lands under the LN2 epilogue) ----
  STAGE_W1F(0);
  STAGE_W2F(0);
  if (w < 4) gload16(b1 + (size_t)(w * 256 + lane * 4), b1l + w * 256 + lane * 4);
  // ---- phase 3: xw += bp + x (residual); LN2 stats ----
  float s1 = 0.f, s2 = 0.f;
#pragma unroll
  for (int j = 0; j < 2; ++j) {
#pragma unroll
    for (int q = 0; q < 4; ++q) {
      int n = fq * 64 + j * 32 + q * 8 + h * 4;
      size_t off = (size_t)m * 256 + n;
      const float4 bv = *reinterpret_cast<const float4*>(&bp[n]);
      const float4 rv = *reinterpret_cast<const float4*>(&x[off]);
      float o0 = xw[j][q * 4 + 0] + bv.x + rv.x;
      float o1 = xw[j][q * 4 + 1] + bv.y + rv.y;
      float o2 = xw[j][q * 4 + 2] + bv.z + rv.z;
      float o3 = xw[j][q * 4 + 3] + bv.w + rv.w;
      xw[j][q * 4 + 0] = o0; xw[j][q * 4 + 1] = o1;
      xw[j][q * 4 + 2] = o2; xw[j][q * 4 + 3] = o3;
      s1 += (o0 + o1) + (o2 + o3);
      s2 += (o0 * o0 + o1 * o1) + (o2 * o2 + o3 * o3);
    }
  }
  // reduce across h (lanes l32 / l32+32), then across fq waves via LDS
  s1 += __shfl_xor(s1, 32, 64);
  s2 += __shfl_xor(s2, 32, 64);
  if (h == 0) { red[fq][ar][0] = s1; red[fq][ar][1] = s2; }
  wait_lgkm0();
  sbar();
  {
    float S1 = (red[0][ar][0] + red[1][ar][0]) + (red[2][ar][0] + red[3][ar][0]);
    float S2 = (red[0][ar][1] + red[1][ar][1]) + (red[2][ar][1] + red[3][ar][1]);
    float mu = S1 * (1.0f / 256.0f);
    float inv = rsqrtf(fmaxf(S2 * (1.0f / 256.0f) - mu * mu, 0.0f) + LN_EPS);
    // LN2 -> hb fp8 pkrow (global; read back below for the k-exchange)
#pragma unroll
    for (int j = 0; j < 2; ++j) {
#pragma unroll
      for (int q = 0; q < 4; ++q) {
        int n = fq * 64 + j * 32 + q * 8 + h * 4;
        const float4 gv = *reinterpret_cast<const float4*>(&g2[n]);
        const float4 bb = *reinterpret_cast<const float4*>(&be2[n]);
        u32 pk = f2f8x4(gv.x * (xw[j][q * 4 + 0] - mu) * inv + bb.x,
                        gv.y * (xw[j][q * 4 + 1] - mu) * inv + bb.y,
                        gv.z * (xw[j][q * 4 + 2] - mu) * inv + bb.z,
                        gv.w * (xw[j][q * 4 + 3] - mu) * inv + bb.w);
        *reinterpret_cast<u32*>(hb + (size_t)m * 256 + pkrow(m, n)) = pk;
      }
    }
  }
  wait_vm0();  // hb stores retired to L2 + W1/W2/b1 staging landed
  sbar();      // all waves' hb rows visible
  // ---- phase 4: ffn A-frags from hb (L2-hot) ----
  i64x2 aa[4][2];
#pragma unroll
  for (int kg = 0; kg < 4; ++kg)
#pragma unroll
    for (int p = 0; p < 2; ++p)
      aa[kg][p] = *reinterpret_cast<const i64x2*>(
          hb + (size_t)(m0 + ar) * 256 + kg * 64 + ((((h << 1) + p) ^ az) << 4));

  // ---- phase 5: ffn loop (v9 structure, proven) ----
  f32x16 acc2[2] = {};
#pragma unroll 1
  for (int nb = 0; nb < 8; ++nb) {
    wait_vm4();  // W1(nb) landed; W2(nb)'s 4 loads stay in flight
    sbar();
    // GEMM1
    f32x16 a1 = {};
    __builtin_amdgcn_s_setprio(1);
#pragma unroll
    for (int kg = 0; kg < 4; ++kg) {
      int br = fq * 32 + l32, bz = swz3i(br);
#pragma unroll
      for (int p = 0; p < 2; ++p) {
        i64x2 bB = *reinterpret_cast<const i64x2*>(
            &Bw[kg * 8192 + br * 64 + ((((h << 1) + p) ^ bz) << 4)]);
        a1 = __builtin_amdgcn_mfma_f32_32x32x16_fp8_fp8(
            bB[0], aa[kg][p][0], a1, 0, 0, 0);
        a1 = __builtin_amdgcn_mfma_f32_32x32x16_fp8_fp8(
            bB[1], aa[kg][p][1], a1, 0, 0, 0);
      }
    }
    __builtin_amdgcn_s_setprio(0);
    // swish -> Ff
    int kg2w = fq >> 1;
    {
      int tz = swz3i(ar);
#pragma unroll
      for (int q = 0; q < 4; ++q) {
        int g = (fq & 1) * 2 + (q >> 1);
        int hh = q & 1;
        int c = (hh << 1) + (g >> 1);
        const float4 bv = *reinterpret_cast<const float4*>(
            &b1l[nb * 128 + fq * 32 + q * 8 + h * 4]);
        float bf[4] = {bv.x, bv.y, bv.z, bv.w};
        float sv[4];
#pragma unroll
        for (int r = 0; r < 4; ++r) {
          float fv = a1[q * 4 + r] + bf[r];
          float e = __builtin_amdgcn_exp2f(fv * -1.44269504f);
          sv[r] = fv * __builtin_amdgcn_rcpf(1.0f + e);
        }
        *reinterpret_cast<u32*>(
            &Ff[kg2w][ar][((c ^ tz) << 4) + ((g & 1) << 3) + h * 4]) =
            f2f8x4(sv[0], sv[1], sv[2], sv[3]);
      }
    }
    wait_vm0_lgkm0();  // W2(nb) landed + Ff writes done
    sbar();            // mid barrier: Bw1 reads done + Ff visible
    if (nb < 7) STAGE_W1F(nb + 1);  // overlaps GEMM2
    // GEMM2
    __builtin_amdgcn_s_setprio(1);
#pragma unroll
    for (int kg2 = 0; kg2 < 2; ++kg2)
#pragma unroll
      for (int p = 0; p < 2; ++p) {
        i64x2 fa = *reinterpret_cast<const i64x2*>(
            &Ff[kg2][ar][(((h << 1) + p) ^ swz3i(ar)) << 4]);
        i64x2 bb2[2];
#pragma unroll
        for (int j = 0; j < 2; ++j) {
          int br = fq * 64 + j * 32 + l32;
          bb2[j] = *reinterpret_cast<const i64x2*>(
              &Bw[32768 + kg2 * 16384 + br * 64 +
                  ((((h << 1) + p) ^ swz3i(br)) << 4)]);
        }
#pragma unroll
        for (int j = 0; j < 2; ++j) {
          acc2[j] = __builtin_amdgcn_mfma_f32_32x32x16_fp8_fp8(
              bb2[j][0], fa[0], acc2[j], 0, 0, 0);
          acc2[j] = __builtin_amdgcn_mfma_f32_32x32x16_fp8_fp8(
              bb2[j][1], fa[1], acc2[j], 0, 0, 0);
        }
      }
    __builtin_amdgcn_s_setprio(0);
    sbar();  // all waves done reading Bw2 + Ff
    if (nb < 7) STAGE_W2F(nb + 1);  // overlaps next GEMM1 + swish
  }
#undef STAGE_W1F
#undef STAGE_W2F
  // ---- epilogue: out = acc2 + b2 + xw (register residual) ----
#pragma unroll
  for (int j = 0; j < 2; ++j) {
#pragma unroll
    for (int q = 0; q < 4; ++q) {
      int n = fq * 64 + j * 32 + q * 8 + h * 4;
      size_t off = (size_t)m * 256 + n;
      const float4 bv = *reinterpret_cast<const float4*>(&b2[n]);
      float4 o;
      o.x = acc2[j][q * 4 + 0] + bv.x + xw[j][q * 4 + 0];
      o.y = acc2[j][q * 4 + 1] + bv.y + xw[j][q * 4 + 1];
      o.z = acc2[j][q * 4 + 2] + bv.z + xw[j][q * 4 + 2];
      o.w = acc2[j][q * 4 + 3] + bv.w + xw[j][q * 4 + 3];
      *reinterpret_cast<float4*>(&outp[off]) = o;
    }
  }
}

// ---------------- attention v9: head-major in AND out -----------------------
__global__ __launch_bounds__(256) void attn_kernel(const u8* __restrict__ kq8,
                                                   const u16* __restrict__ v16,
                                                   u8* __restrict__ o8) {
  __shared__ u8 q8[256 * 48];       // 12KB (rows stride 48B)
  __shared__ u16 vT[32 * 256];      // 16KB
  __shared__ u16 pT[4 * 16 * 64];   //  8KB (1 region per wave)
  int bh = blockIdx.x;
  int b = bh >> 3, h = bh & 7;
  int tid = threadIdx.x, wid = tid >> 6, lane = tid & 63;
  int l16 = lane & 15, lh = lane >> 4;
  const u8* kqh = kq8 + ((size_t)h * NT + (size_t)b * TT) * 64;
  const u16* vh = v16 + ((size_t)h * NT + (size_t)b * TT) * 32;
  u8* oh = o8 + ((size_t)h * NT + (size_t)b * TT) * 32;
  {
    int sr = tid >> 2, c = tid & 3;
    for (int s = sr; s < 256; s += 64) {
      // Q: 32B/row fp8 (2 chunks; c<2)
      if (c < 2) {
        uint4 qv = *reinterpret_cast<const uint4*>(
            &kqh[(size_t)s * 64 + 32 + c * 16]);
        *reinterpret_cast<uint4*>(&q8[s * 48 + c * 16]) = qv;
      }
      // V: 64B/row bf16 (4 chunks), transposed into vT
      u16 tmp[8];
      *reinterpret_cast<uint4*>(tmp) = *reinterpret_cast<const uint4*>(
          &vh[(size_t)s * 32 + c * 8]);
#pragma unroll
      for (int e = 0; e < 8; ++e) {
        int d = c * 8 + e;
        vT[d * 256 + (((s >> 3) ^ ((d >> 1) & 7)) << 3) + (s & 7)] = tmp[e];
      }
    }
  }
  __syncthreads();
  u16* pw = &pT[wid * 16 * 64];
  const float C1 = 0.09016844f;  // SCALE * log2(e)
#pragma unroll
  for (int pp = 0; pp < 2; ++pp) {
    const int jA = 2 * pp, jB = 2 * pp + 1;
    int tA16 = (jA * 4 + wid) * 16, tB16 = (jB * 4 + wid) * 16;
    long kbA = *reinterpret_cast<const long*>(
        &kqh[(size_t)(tA16 + l16) * 64 + lh * 8]);
    long kbB = *reinterpret_cast<const long*>(
        &kqh[(size_t)(tB16 + l16) * 64 + lh * 8]);
    float m2A = -3e38f, m2B = -3e38f, lsA = 0.f, lsB = 0.f;
    f32x4 oA[2] = {}, oB[2] = {};
#pragma unroll
    for (int st = 0; st <= jB; ++st) {
      const bool actA = (st <= jA);  // compile-time after unroll
      int s0 = st << 6;
      float vA[4][4], vB[4][4], pmA[4], pmB[4];
#pragma unroll
      for (int sj = 0; sj < 4; ++sj) {
        int srow = s0 + sj * 16 + l16;
        long qa = *reinterpret_cast<const long*>(&q8[srow * 48 + lh * 8]);
        f32x4 z = {0.f, 0.f, 0.f, 0.f};
        f32x4 scB = __builtin_amdgcn_mfma_f32_16x16x32_fp8_fp8(qa, kbB, z, 0, 0, 0);
#pragma unroll
        for (int r = 0; r < 4; ++r) {
          float vb_ = scB[r];
          if (st == jB) {
            if (sj * 16 + lh * 4 + r > wid * 16 + l16) vb_ = -3e38f;
          }
          vB[sj][r] = vb_;
        }
        pmB[sj] = fmaxf(fmaxf(vB[sj][0], vB[sj][1]), fmaxf(vB[sj][2], vB[sj][3]));
        if (actA) {
          f32x4 scA = __builtin_amdgcn_mfma_f32_16x16x32_fp8_fp8(qa, kbA, z, 0, 0, 0);
#pragma unroll
          for (int r = 0; r < 4; ++r) {
            float va_ = scA[r];
            if (st == jA) {
              if (sj * 16 + lh * 4 + r > wid * 16 + l16) va_ = -3e38f;
            }
            vA[sj][r] = va_;
          }
          pmA[sj] = fmaxf(fmaxf(vA[sj][0], vA[sj][1]), fmaxf(vA[sj][2], vA[sj][3]));
        }
      }
      // ---- chain A: softmax -> pw -> PV-A ----
      if (actA) {
        float mx = fmaxf(fmaxf(pmA[0], pmA[1]), fmaxf(pmA[2], pmA[3]));
        mx = fmaxf(mx, __shfl_xor(mx, 16, 64));
        mx = fmaxf(mx, __shfl_xor(mx, 32, 64));
        float mxs = mx * C1;
        if (!__all(mxs <= m2A + 8.0f)) {
          float mn = fmaxf(m2A, mxs);
          float alpha = exp2f(m2A - mn);
          m2A = mn;
          lsA *= alpha;
#pragma unroll
          for (int r = 0; r < 4; ++r) {
            float a = __shfl(alpha, (lane & 48) | (lh * 4 + r), 64);
            oA[0][r] *= a;
            oA[1][r] *= a;
          }
        }
#pragma unroll
        for (int sj = 0; sj < 4; ++sj) {
          float p0 = exp2f(__builtin_fmaf(vA[sj][0], C1, -m2A));
          float p1 = exp2f(__builtin_fmaf(vA[sj][1], C1, -m2A));
          float p2 = exp2f(__builtin_fmaf(vA[sj][2], C1, -m2A));
          float p3 = exp2f(__builtin_fmaf(vA[sj][3], C1, -m2A));
          lsA += (p0 + p1) + (p2 + p3);
          uint2 pkv = f2bfx4(p0, p1, p2, p3);
          *reinterpret_cast<uint2*>(
              (char*)pw + ((l16 * 128 + sj * 32 + lh * 8) ^ ((l16 & 7) << 4))) = pkv;
        }
#pragma unroll
        for (int ks = 0; ks < 2; ++ks) {
          bf16x8 pa = *reinterpret_cast<const bf16x8*>(
              (char*)pw + ((l16 * 128 + ks * 64 + lh * 16) ^ ((l16 & 7) << 4)));
#pragma unroll
          for (int nI = 0; nI < 2; ++nI) {
            int d = nI * 16 + l16;
            int sch = ((s0 + ks * 32 + lh * 8) >> 3) ^ ((d >> 1) & 7);
            bf16x8 vb = *reinterpret_cast<const bf16x8*>(&vT[d * 256 + (sch << 3)]);
            oA[nI] = __builtin_amdgcn_mfma_f32_16x16x32_bf16(pa, vb, oA[nI], 0, 0, 0);
          }
        }
      }
      // ---- chain B: softmax -> pw (reuse; wave-private, DS in-order) -> PV-B
      {
        float mx = fmaxf(fmaxf(pmB[0], pmB[1]), fmaxf(pmB[2], pmB[3]));
        mx = fmaxf(mx, __shfl_xor(mx, 16, 64));
        mx = fmaxf(mx, __shfl_xor(mx, 32, 64));
        float mxs = mx * C1;
        if (!__all(mxs <= m2B + 8.0f)) {
          float mn = fmaxf(m2B, mxs);
          float alpha = exp2f(m2B - mn);
          m2B = mn;
          lsB *= alpha;
#pragma unroll
          for (int r = 0; r < 4; ++r) {
            float a = __shfl(alpha, (lane & 48) | (lh * 4 + r), 64);
            oB[0][r] *= a;
            oB[1][r] *= a;
          }
        }
#pragma unroll
        for (int sj = 0; sj < 4; ++sj) {
          float p0 = exp2f(__builtin_fmaf(vB[sj][0], C1, -m2B));
          float p1 = exp2f(__builtin_fmaf(vB[sj][1], C1, -m2B));
          float p2 = exp2f(__builtin_fmaf(vB[sj][2], C1, -m2B));
          float p3 = exp2f(__builtin_fmaf(vB[sj][3], C1, -m2B));
          lsB += (p0 + p1) + (p2 + p3);
          uint2 pkv = f2bfx4(p0, p1, p2, p3);
          *reinterpret_cast<uint2*>(
              (char*)pw + ((l16 * 128 + sj * 32 + lh * 8) ^ ((l16 & 7) << 4))) = pkv;
        }
#pragma unroll
        for (int ks = 0; ks < 2; ++ks) {
          bf16x8 pa = *reinterpret_cast<const bf16x8*>(
              (char*)pw + ((l16 * 128 + ks * 64 + lh * 16) ^ ((l16 & 7) << 4)));
#pragma unroll
          for (int nI = 0; nI < 2; ++nI) {
            int d = nI * 16 + l16;
            int sch = ((s0 + ks * 32 + lh * 8) >> 3) ^ ((d >> 1) & 7);
            bf16x8 vb = *reinterpret_cast<const bf16x8*>(&vT[d * 256 + (sch << 3)]);
            oB[nI] = __builtin_amdgcn_mfma_f32_16x16x32_bf16(pa, vb, oB[nI], 0, 0, 0);
          }
        }
      }
    }
    // ---- reduce + output both chains (head-major o8h) ----
    lsA += __shfl_xor(lsA, 16, 64);
    lsA += __shfl_xor(lsA, 32, 64);
    lsB += __shfl_xor(lsB, 16, 64);
    lsB += __shfl_xor(lsB, 32, 64);
    int obyte = (l16 >> 3) * 16 + (l16 & 7);
#pragma unroll
    for (int r = 0; r < 4; ++r) {
      float laA = __shfl(lsA, (lane & 48) | (lh * 4 + r), 64);
      float laB = __shfl(lsB, (lane & 48) | (lh * 4 + r), 64);
      float invA = 1.0f / laA, invB = 1.0f / laB;
      int tA = tA16 + lh * 4 + r, tB = tB16 + lh * 4 + r;
#pragma unroll
      for (int nI = 0; nI < 2; ++nI) {
        oh[(size_t)tA * 32 + obyte + nI * 8] = f2f8(oA[nI][r] * invA);
        oh[(size_t)tB * 32 + obyte + nI * 8] = f2f8(oB[nI][r] * invB);
      }
    }
  }
}

// ---------------- launch ----------------------------------------------------
extern "C" void kernel_launch(void* const* d_in, const int* in_sizes, int n_in,
                              void* d_out, int out_size, void* d_ws, size_t ws_size,
                              hipStream_t stream) {
  const float* x   = (const float*)d_in[0];
  const float* Wk  = (const float*)d_in[1];
  const float* Wq  = (const float*)d_in[2];
  const float* Wv  = (const float*)d_in[3];
  const float* Wp  = (const float*)d_in[4];
  const float* bp  = (const float*)d_in[5];
  const float* W1  = (const float*)d_in[6];
  const float* b1  = (const float*)d_in[7];
  const float* W2  = (const float*)d_in[8];
  const float* b2  = (const float*)d_in[9];
  const float* g1  = (const float*)d_in[10];
  const float* be1 = (const float*)d_in[11];
  const float* g2  = (const float*)d_in[12];
  const float* be2 = (const float*)d_in[13];

  char* ws = (char*)d_ws;
  u8*  kq8 = (u8*)(ws + 0);                   // [H][NT][64] fp8 K|Q head-major (16MB)
  u16* v16 = (u16*)(ws + 16777216);           // [H][NT][32] bf16 V head-major (16MB)
  u8*  o8  = (u8*)(ws + 50331648);            // [H][NT][32] fp8 head-major (8MB)
  u8*  hb  = (u8*)(ws + 100663296);           // [NT][256] fp8: LN1 out, then LN2 out
  char* wb = ws + 117440512;
  u8*  WkqvT8 = (u8*)(wb);                    // 192KB
  u8*  WpT8   = (u8*)(wb + 196608);           // 64KB
  u8*  W1T8   = (u8*)(wb + 196608 + 65536);   // 256KB
  u8*  W2T8   = (u8*)(wb + 196608 + 65536 + 262144);  // 256KB

  // fused: weight conversion (blocks 0..191) + LN1 (blocks 192..8383)
  conv_ln<<<192 + NT / 4, 256, 0, stream>>>(Wk, Wq, Wv, Wp, W1, W2,
                                            WkqvT8, WpT8, W1T8, W2T8,
                                            x, g1, be1, hb);
  qkv_fused<<<NT / 64, 512, 0, stream>>>(hb, WkqvT8, kq8, v16);
  attn_kernel<<<BB * HH, 256, 0, stream>>>(kq8, v16, o8);
  // FUSED: Wp + bias + residual + LN2 + FFN + final residual -> d_out
  wp_ffn<<<NT / 64, 512, 0, stream>>>(o8, WpT8, bp, x, W1T8, W2T8,
                                      b1, b2, g2, be2, hb, (float*)d_out);
}

// Round 28
// 119.274 us; speedup vs baseline: 1.0030x; 1.0030x over previous
//
#include <hip/hip_runtime.h>
#include <cstdint>

#define BB 128
#define TT 256
#define CC 256
#define HH 8
#define HSZ 32
#define NT (BB*TT)      // 32768 tokens
#define CF (4*CC)       // 1024
#define LN_EPS 1e-5f
#define SCALE 0.0625f   // C^-0.5 = 256^-0.5

typedef __attribute__((ext_vector_type(8))) __bf16 bf16x8;
typedef __attribute__((ext_vector_type(4))) float f32x4;
typedef __attribute__((ext_vector_type(16))) float f32x16;
typedef __attribute__((ext_vector_type(2))) long i64x2;
typedef unsigned short u16;
typedef unsigned int u32;
typedef unsigned char u8;

__device__ __forceinline__ u16 f2bf(float f) {
  u32 u = __float_as_uint(f);
  u32 r = (u + 0x7fffu + ((u >> 16) & 1u)) >> 16;
  return (u16)r;
}
__device__ __forceinline__ u8 f2f8(float f) {
  return (u8)(__builtin_amdgcn_cvt_pk_fp8_f32(f, f, 0, false) & 0xff);
}
// pack 4 floats -> 4 fp8 bytes (byte r = element r)
__device__ __forceinline__ u32 f2f8x4(float a, float b, float c, float d) {
  u32 pk = (u32)__builtin_amdgcn_cvt_pk_fp8_f32(a, b, 0, false);
  return (u32)__builtin_amdgcn_cvt_pk_fp8_f32(c, d, (int)pk, true);
}
// pack 4 floats -> 4 bf16 (packed HW cvt; no builtin on gfx950 -> inline asm)
__device__ __forceinline__ uint2 f2bfx4(float a, float b, float c, float d) {
  uint2 r;
  asm("v_cvt_pk_bf16_f32 %0, %1, %2" : "=v"(r.x) : "v"(a), "v"(b));
  asm("v_cvt_pk_bf16_f32 %0, %1, %2" : "=v"(r.y) : "v"(c), "v"(d));
  return r;
}
// pkrow: 32x32x16-fp8 fragment interleave + swz3 bank swizzle baked into
// GLOBAL layouts (within each 64-B k-group). Staging = PURE LINEAR copy.
__device__ __forceinline__ int swz3i(int r) { return (r ^ (r >> 2)) & 3; }
__device__ __forceinline__ int pkrow(int row, int k) {
  int g = (k >> 4) & 3, h = (k >> 3) & 1, j = k & 7;
  int c = (h << 1) + (g >> 1);
  int cp = c ^ swz3i(row);
  return (k & ~63) + cp * 16 + ((g & 1) << 3) + j;
}

__device__ __forceinline__ void gload16(const void* g, void* l) {
  __builtin_amdgcn_global_load_lds(
      (const __attribute__((address_space(1))) u32*)(uintptr_t)g,
      (__attribute__((address_space(3))) u32*)(u32)(uintptr_t)l,
      16, 0, 0);
}

// counted waits (T4) only in proven steady-state loops; prologues use full
// drains (R11/R12/R13/R16 lesson: reordering or count-discriminating the
// prologue's VMEM groups is unsafe or negative -- family closed).
__device__ __forceinline__ void wait_vm0() {
  asm volatile("s_waitcnt vmcnt(0)" ::: "memory");
  __builtin_amdgcn_sched_barrier(0);
}
__device__ __forceinline__ void wait_vm4() {
  asm volatile("s_waitcnt vmcnt(4)" ::: "memory");
  __builtin_amdgcn_sched_barrier(0);
}
__device__ __forceinline__ void wait_vm8() {
  asm volatile("s_waitcnt vmcnt(8)" ::: "memory");
  __builtin_amdgcn_sched_barrier(0);
}
__device__ __forceinline__ void wait_vm0_lgkm0() {
  asm volatile("s_waitcnt vmcnt(0) lgkmcnt(0)" ::: "memory");
  __builtin_amdgcn_sched_barrier(0);
}
__device__ __forceinline__ void wait_lgkm0() {
  asm volatile("s_waitcnt lgkmcnt(0)" ::: "memory");
  __builtin_amdgcn_sched_barrier(0);
}
__device__ __forceinline__ void sbar() {
  __builtin_amdgcn_s_barrier();
  __builtin_amdgcn_sched_barrier(0);
}

// ---- conv_ln: fused weight transpose-convert (blocks 0..191) + LN1
// (blocks 192..8383).
__global__ __launch_bounds__(256) void conv_ln(
    const float* __restrict__ Wk, const float* __restrict__ Wq,
    const float* __restrict__ Wv, const float* __restrict__ Wp,
    const float* __restrict__ W1, const float* __restrict__ W2,
    u8* __restrict__ WkqvT8, u8* __restrict__ WpT8,
    u8* __restrict__ W1T8, u8* __restrict__ W2T8,
    const float* __restrict__ x, const float* __restrict__ g1,
    const float* __restrict__ be1, u8* __restrict__ hb) {
  __shared__ u8 ldsT[64][68];
  int bid = blockIdx.x, tid = threadIdx.x;
  if (bid >= 192) {
    // ---------------- LN1 ----------------
    int wid = tid >> 6, lane = tid & 63;
    int row = (bid - 192) * 4 + wid;
    const float4 v = reinterpret_cast<const float4*>(x + (size_t)row * CC)[lane];
    float s = v.x + v.y + v.z + v.w;
#pragma unroll
    for (int o = 32; o; o >>= 1) s += __shfl_xor(s, o, 64);
    float mu = s * (1.0f / CC);
    float dx = v.x - mu, dy = v.y - mu, dz = v.z - mu, dw = v.w - mu;
    float ss = dx * dx + dy * dy + dz * dz + dw * dw;
#pragma unroll
    for (int o = 32; o; o >>= 1) ss += __shfl_xor(ss, o, 64);
    float inv = rsqrtf(ss * (1.0f / CC) + LN_EPS);
    const float4 gv = reinterpret_cast<const float4*>(g1)[lane];
    const float4 bv = reinterpret_cast<const float4*>(be1)[lane];
    u32 pk = f2f8x4(gv.x * dx * inv + bv.x, gv.y * dy * inv + bv.y,
                    gv.z * dz * inv + bv.z, gv.w * dw * inv + bv.w);
    *reinterpret_cast<u32*>(hb + (size_t)row * CC + pkrow(row, lane * 4)) = pk;
    return;
  }
  // ---------------- conv_t ----------------
  int n0, k0, K;
  u8* dst;
  int mode;  // 0 = kqv (piecewise head addressing), 1 = linear
  const float* src = nullptr;
  int sk = 0;
  if (bid < 48) {
    mode = 0; n0 = (bid >> 2) * 64; k0 = (bid & 3) * 64; K = 256; dst = WkqvT8;
  } else if (bid < 112) {
    int l = bid - 48;
    mode = 1; n0 = (l >> 2) * 64; k0 = (l & 3) * 64; K = 256; dst = W1T8;
    src = W1; sk = 1024;
  } else if (bid < 176) {
    int l = bid - 112;
    mode = 1; n0 = (l >> 4) * 64; k0 = (l & 15) * 64; K = 1024; dst = W2T8;
    src = W2; sk = 256;
  } else {
    int l = bid - 176;
    mode = 1; n0 = (l >> 2) * 64; k0 = (l & 3) * 64; K = 256; dst = WpT8;
    src = Wp; sk = 256;
  }
  int kr = tid >> 2;               // k-row 0..63
  int nbase = (tid & 3) * 16;      // n-chunk
#pragma unroll
  for (int u = 0; u < 4; ++u) {
    int nl = nbase + u * 4;
    int ng = n0 + nl;
    float4 v;
    if (mode == 0) {
      const float* W = (ng < 256) ? Wk : (ng < 512 ? Wq : Wv);
      int inner = ng & 255;
      v = *reinterpret_cast<const float4*>(
          &W[((inner >> 5) << 13) + (size_t)(k0 + kr) * 32 + (inner & 31)]);
    } else {
      v = *reinterpret_cast<const float4*>(
          &src[(size_t)(k0 + kr) * sk + ng]);
    }
    ldsT[nl + 0][kr] = f2f8(v.x);
    ldsT[nl + 1][kr] = f2f8(v.y);
    ldsT[nl + 2][kr] = f2f8(v.z);
    ldsT[nl + 3][kr] = f2f8(v.w);
  }
  __syncthreads();
  int nl = tid >> 2;
  int nglob = n0 + nl;
  int sz = swz3i(nglob);
  u8* drow = dst + (size_t)nglob * K + k0;
#pragma unroll
  for (int c4 = (tid & 3) * 4; c4 < (tid & 3) * 4 + 4; ++c4) {
    int q = c4 >> 1, s = c4 & 1;
    int kb = q * 8 + s * 4;        // k%8 in {0,4}: contiguous under pkrow
    u32 pk = (u32)ldsT[nl][kb] | ((u32)ldsT[nl][kb + 1] << 8) |
             ((u32)ldsT[nl][kb + 2] << 16) | ((u32)ldsT[nl][kb + 3] << 24);
    int g = (kb >> 4) & 3, h8 = (kb >> 3) & 1;
    int cp = ((h8 << 1) + (g >> 1)) ^ sz;
    *reinterpret_cast<u32*>(drow + cp * 16 + ((g & 1) << 3) + (kb & 7)) = pk;
  }
}

// ---- qkv_fused: QKV GEMM (NB=3 panels). Outputs HEAD-MAJOR:
//   kq8h[h][NT][64B]  (K bytes 0..31, Q bytes 32..63, fp8)
//   v16h[h][NT][32]   (bf16)
__global__ __launch_bounds__(512, 4) void qkv_fused(
    const u8* __restrict__ Asrc, const u8* __restrict__ WT8,
    u8* __restrict__ kq8, u16* __restrict__ v16) {
  __shared__ u8 Bw[4][256][64];   // weight panel [kg][n][64B]  64KB
  int tid = threadIdx.x;
  int w = tid >> 6, lane = tid & 63;
  int l32 = lane & 31, h = lane >> 5;
  int th = w >> 2, fq = w & 3;   // token 32-group, n 64-quarter
  int m0 = blockIdx.x * 64;

#define STAGEP(nb)                                                            \
  {                                                                           \
    _Pragma("unroll") for (int it = 0; it < 8; ++it) {                        \
      int f = it * 512 + tid;                                                 \
      int kg = f >> 10, t = (f >> 2) & 255, c = f & 3;                        \
      gload16(WT8 + (size_t)((nb) * 256 + t) * 256 + kg * 64 + c * 16,        \
              &Bw[0][0][0] + f * 16);                                         \
    }                                                                         \
  }
  // A-fragments -> registers (issued FIRST: oldest in vmcnt FIFO)
  i64x2 aa[4][2];
  {
    int ar = th * 32 + l32;
    int az = swz3i(ar);
#pragma unroll
    for (int kg = 0; kg < 4; ++kg)
#pragma unroll
      for (int p = 0; p < 2; ++p)
        aa[kg][p] = *reinterpret_cast<const i64x2*>(
            Asrc + (size_t)(m0 + ar) * 256 + kg * 64 +
            ((((h << 1) + p) ^ az) << 4));
  }
  STAGEP(0);

#pragma unroll 1
  for (int nb = 0; nb < 3; ++nb) {
    if (nb == 0) wait_vm0(); else wait_vm8();
    sbar();  // panel nb staged & visible to all waves
    f32x16 a1[2] = {};
    __builtin_amdgcn_s_setprio(1);
#pragma unroll
    for (int kg = 0; kg < 4; ++kg) {
#pragma unroll
      for (int p = 0; p < 2; ++p) {
        i64x2 bB[2];
#pragma unroll
        for (int j = 0; j < 2; ++j) {
          int br = fq * 64 + j * 32 + l32, bz = swz3i(br);
          bB[j] = *reinterpret_cast<const i64x2*>(
              &Bw[kg][br][(((h << 1) + p) ^ bz) << 4]);
        }
#pragma unroll
        for (int j = 0; j < 2; ++j) {
          a1[j] = __builtin_amdgcn_mfma_f32_32x32x16_fp8_fp8(
              bB[j][0], aa[kg][p][0], a1[j], 0, 0, 0);
          a1[j] = __builtin_amdgcn_mfma_f32_32x32x16_fp8_fp8(
              bB[j][1], aa[kg][p][1], a1[j], 0, 0, 0);
        }
      }
    }
    __builtin_amdgcn_s_setprio(0);
    sbar();  // all waves done reading Bw
    if (nb < 2) STAGEP(nb + 1);  // prefetch; lands under stores + GEMM
    int m = m0 + th * 32 + l32;
#pragma unroll
    for (int j = 0; j < 2; ++j) {
#pragma unroll
      for (int q = 0; q < 4; ++q) {
        int n = nb * 256 + fq * 64 + j * 32 + q * 8 + h * 4;
        if (n < 256) {
          // K -> fp8, head-major, bytes 0..31 of 64B row
          u32 pk = f2f8x4(a1[j][q * 4 + 0], a1[j][q * 4 + 1],
                          a1[j][q * 4 + 2], a1[j][q * 4 + 3]);
          int hh2 = n >> 5, col = n & 31;
          *reinterpret_cast<u32*>(
              &kq8[((size_t)hh2 * NT + m) * 64 + col]) = pk;
        } else if (n < 512) {
          // Q -> fp8, head-major, bytes 32..63 of 64B row
          u32 pk = f2f8x4(a1[j][q * 4 + 0], a1[j][q * 4 + 1],
                          a1[j][q * 4 + 2], a1[j][q * 4 + 3]);
          int nn = n - 256;
          int hh2 = nn >> 5, col = nn & 31;
          *reinterpret_cast<u32*>(
              &kq8[((size_t)hh2 * NT + m) * 64 + 32 + col]) = pk;
        } else {
          // V -> bf16, head-major (32 u16 = 64B rows)
          u16 pk[4];
#pragma unroll
          for (int r = 0; r < 4; ++r) pk[r] = f2bf(a1[j][q * 4 + r]);
          int nn = n - 512;
          int hh2 = nn >> 5, col = nn & 31;
          *reinterpret_cast<uint2*>(
              &v16[((size_t)hh2 * NT + m) * 32 + col]) =
              *reinterpret_cast<uint2*>(pk);
        }
      }
    }
  }
#undef STAGEP
}

// ---- wp_ffn: R10/R15 structure (proven). o8 HEAD-MAJOR unswizzled:
// o8h[head][NT][32], fragment chunk (kg,p) = 16B at o8h[kg*2+p][m][(lane>>5)*16]
__global__ __launch_bounds__(512, 4) void wp_ffn(
    const u8* __restrict__ o8, const u8* __restrict__ WpT8,
    const float* __restrict__ bp, const float* __restrict__ x,
    const u8* __restrict__ W1T8, const u8* __restrict__ W2T8,
    const float* __restrict__ b1, const float* __restrict__ b2,
    const float* __restrict__ g2, const float* __restrict__ be2,
    u8* __restrict__ hb, float* __restrict__ outp) {
  __shared__ u8 Bw[65536];        // Wp [4][256][64] | W1 @0 [4][128][64] + W2 @32768 [2][256][64]
  __shared__ u8 Ff[2][64][64];    // f exchange       8KB
  __shared__ float b1l[1024];     // b1 staged        4KB
  __shared__ float red[4][64][2]; // LN2 reduce       2KB   (total 78KB)
  int tid = threadIdx.x;
  int w = tid >> 6, lane = tid & 63;
  int l32 = lane & 31, h = lane >> 5;
  int th = w >> 2, fq = w & 3;
  int m0 = blockIdx.x * 64;
  int m = m0 + th * 32 + l32;
  int ar = th * 32 + l32, az = swz3i(ar);

#define STAGE_W1F(nb)                                                         \
  {                                                                           \
    _Pragma("unroll") for (int it = 0; it < 4; ++it) {                        \
      int f = it * 512 + tid;                                                 \
      int kg = f >> 9, t = (f >> 2) & 127, c = f & 3;                         \
      gload16(W1T8 + (size_t)((nb) * 128 + t) * 256 + kg * 64 + c * 16,       \
              Bw + f * 16);                                                   \
    }                                                                         \
  }
#define STAGE_W2F(nb)                                                         \
  {                                                                           \
    _Pragma("unroll") for (int it = 0; it < 4; ++it) {                        \
      int f = it * 512 + tid;                                                 \
      int kg2 = f >> 10, o = (f >> 2) & 255, c = f & 3;                       \
      gload16(W2T8 + (size_t)o * 1024 + (nb) * 128 + kg2 * 64 + c * 16,       \
              Bw + 32768 + f * 16);                                           \
    }                                                                         \
  }

  // ---- phase 0: o8 A-frags (head-major) + Wp panel (64KB) staging ----
  i64x2 aw[4][2];
#pragma unroll
  for (int kg = 0; kg < 4; ++kg)
#pragma unroll
    for (int p = 0; p < 2; ++p)
      aw[kg][p] = *reinterpret_cast<const i64x2*>(
          o8 + ((size_t)(kg * 2 + p) * NT + (m0 + ar)) * 32 + h * 16);
  {
#pragma unroll
    for (int it = 0; it < 8; ++it) {
      int f = it * 512 + tid;
      int kg = f >> 10, t = (f >> 2) & 255, c = f & 3;
      gload16(WpT8 + (size_t)t * 256 + kg * 64 + c * 16, Bw + f * 16);
    }
  }
  wait_vm0();
  sbar();
  // ---- phase 1: Wp GEMM -> xw[2] (becomes the x2 residual, registers) ----
  f32x16 xw[2] = {};
  __builtin_amdgcn_s_setprio(1);
#pragma unroll
  for (int kg = 0; kg < 4; ++kg) {
#pragma unroll
    for (int p = 0; p < 2; ++p) {
      i64x2 bB[2];
#pragma unroll
      for (int j = 0; j < 2; ++j) {
        int br = fq * 64 + j * 32 + l32, bz = swz3i(br);
        bB[j] = *reinterpret_cast<const i64x2*>(
            &Bw[kg * 16384 + br * 64 + ((((h << 1) + p) ^ bz) << 4)]);
      }
#pragma unroll
      for (int j = 0; j < 2; ++j) {
        xw[j] = __builtin_amdgcn_mfma_f32_32x32x16_fp8_fp8(
            bB[j][0], aw[kg][p][0], xw[j], 0, 0, 0);
        xw[j] = __builtin_amdgcn_mfma_f32_32x32x16_fp8_fp8(
            bB[j][1], aw[kg][p][1], xw[j], 0, 0, 0);
      }
    }
  }
  __builtin_amdgcn_s_setprio(0);
  sbar();  // all waves done reading the Wp panel -> Bw reusable
  // ---- phase 2: stage W1(0)/W2(0)/b1 (lands under the LN2 epilogue) ----
  STAGE_W1F(0);
  STAGE_W2F(0);
  if (w < 4) gload16(b1 + (size_t)(w * 256 + lane * 4), b1l + w * 256 + lane * 4);
  // ---- phase 3: xw += bp + x (residual); LN2 stats ----
  float s1 = 0.f, s2 = 0.f;
#pragma unroll
  for (int j = 0; j < 2; ++j) {
#pragma unroll
    for (int q = 0; q < 4; ++q) {
      int n = fq * 64 + j * 32 + q * 8 + h * 4;
      size_t off = (size_t)m * 256 + n;
      const float4 bv = *reinterpret_cast<const float4*>(&bp[n]);
      const float4 rv = *reinterpret_cast<const float4*>(&x[off]);
      float o0 = xw[j][q * 4 + 0] + bv.x + rv.x;
      float o1 = xw[j][q * 4 + 1] + bv.y + rv.y;
      float o2 = xw[j][q * 4 + 2] + bv.z + rv.z;
      float o3 = xw[j][q * 4 + 3] + bv.w + rv.w;
      xw[j][q * 4 + 0] = o0; xw[j][q * 4 + 1] = o1;
      xw[j][q * 4 + 2] = o2; xw[j][q * 4 + 3] = o3;
      s1 += (o0 + o1) + (o2 + o3);
      s2 += (o0 * o0 + o1 * o1) + (o2 * o2 + o3 * o3);
    }
  }
  // reduce across h (lanes l32 / l32+32), then across fq waves via LDS
  s1 += __shfl_xor(s1, 32, 64);
  s2 += __shfl_xor(s2, 32, 64);
  if (h == 0) { red[fq][ar][0] = s1; red[fq][ar][1] = s2; }
  wait_lgkm0();
  sbar();
  {
    float S1 = (red[0][ar][0] + red[1][ar][0]) + (red[2][ar][0] + red[3][ar][0]);
    float S2 = (red[0][ar][1] + red[1][ar][1]) + (red[2][ar][1] + red[3][ar][1]);
    float mu = S1 * (1.0f / 256.0f);
    float inv = rsqrtf(fmaxf(S2 * (1.0f / 256.0f) - mu * mu, 0.0f) + LN_EPS);
    // LN2 -> hb fp8 pkrow (global; read back below for the k-exchange)
#pragma unroll
    for (int j = 0; j < 2; ++j) {
#pragma unroll
      for (int q = 0; q < 4; ++q) {
        int n = fq * 64 + j * 32 + q * 8 + h * 4;
        const float4 gv = *reinterpret_cast<const float4*>(&g2[n]);
        const float4 bb = *reinterpret_cast<const float4*>(&be2[n]);
        u32 pk = f2f8x4(gv.x * (xw[j][q * 4 + 0] - mu) * inv + bb.x,
                        gv.y * (xw[j][q * 4 + 1] - mu) * inv + bb.y,
                        gv.z * (xw[j][q * 4 + 2] - mu) * inv + bb.z,
                        gv.w * (xw[j][q * 4 + 3] - mu) * inv + bb.w);
        *reinterpret_cast<u32*>(hb + (size_t)m * 256 + pkrow(m, n)) = pk;
      }
    }
  }
  wait_vm0();  // hb stores retired to L2 + W1/W2/b1 staging landed
  sbar();      // all waves' hb rows visible
  // ---- phase 4: ffn A-frags from hb (L2-hot) ----
  i64x2 aa[4][2];
#pragma unroll
  for (int kg = 0; kg < 4; ++kg)
#pragma unroll
    for (int p = 0; p < 2; ++p)
      aa[kg][p] = *reinterpret_cast<const i64x2*>(
          hb + (size_t)(m0 + ar) * 256 + kg * 64 + ((((h << 1) + p) ^ az) << 4));

  // ---- phase 5: ffn loop (v9 structure, proven) ----
  f32x16 acc2[2] = {};
#pragma unroll 1
  for (int nb = 0; nb < 8; ++nb) {
    wait_vm4();  // W1(nb) landed; W2(nb)'s 4 loads stay in flight
    sbar();
    // GEMM1
    f32x16 a1 = {};
    __builtin_amdgcn_s_setprio(1);
#pragma unroll
    for (int kg = 0; kg < 4; ++kg) {
      int br = fq * 32 + l32, bz = swz3i(br);
#pragma unroll
      for (int p = 0; p < 2; ++p) {
        i64x2 bB = *reinterpret_cast<const i64x2*>(
            &Bw[kg * 8192 + br * 64 + ((((h << 1) + p) ^ bz) << 4)]);
        a1 = __builtin_amdgcn_mfma_f32_32x32x16_fp8_fp8(
            bB[0], aa[kg][p][0], a1, 0, 0, 0);
        a1 = __builtin_amdgcn_mfma_f32_32x32x16_fp8_fp8(
            bB[1], aa[kg][p][1], a1, 0, 0, 0);
      }
    }
    __builtin_amdgcn_s_setprio(0);
    // swish -> Ff
    int kg2w = fq >> 1;
    {
      int tz = swz3i(ar);
#pragma unroll
      for (int q = 0; q < 4; ++q) {
        int g = (fq & 1) * 2 + (q >> 1);
        int hh = q & 1;
        int c = (hh << 1) + (g >> 1);
        const float4 bv = *reinterpret_cast<const float4*>(
            &b1l[nb * 128 + fq * 32 + q * 8 + h * 4]);
        float bf[4] = {bv.x, bv.y, bv.z, bv.w};
        float sv[4];
#pragma unroll
        for (int r = 0; r < 4; ++r) {
          float fv = a1[q * 4 + r] + bf[r];
          float e = __builtin_amdgcn_exp2f(fv * -1.44269504f);
          sv[r] = fv * __builtin_amdgcn_rcpf(1.0f + e);
        }
        *reinterpret_cast<u32*>(
            &Ff[kg2w][ar][((c ^ tz) << 4) + ((g & 1) << 3) + h * 4]) =
            f2f8x4(sv[0], sv[1], sv[2], sv[3]);
      }
    }
    wait_vm0_lgkm0();  // W2(nb) landed + Ff writes done
    sbar();            // mid barrier: Bw1 reads done + Ff visible
    if (nb < 7) STAGE_W1F(nb + 1);  // overlaps GEMM2
    // GEMM2
    __builtin_amdgcn_s_setprio(1);
#pragma unroll
    for (int kg2 = 0; kg2 < 2; ++kg2)
#pragma unroll
      for (int p = 0; p < 2; ++p) {
        i64x2 fa = *reinterpret_cast<const i64x2*>(
            &Ff[kg2][ar][(((h << 1) + p) ^ swz3i(ar)) << 4]);
        i64x2 bb2[2];
#pragma unroll
        for (int j = 0; j < 2; ++j) {
          int br = fq * 64 + j * 32 + l32;
          bb2[j] = *reinterpret_cast<const i64x2*>(
              &Bw[32768 + kg2 * 16384 + br * 64 +
                  ((((h << 1) + p) ^ swz3i(br)) << 4)]);
        }
#pragma unroll
        for (int j = 0; j < 2; ++j) {
          acc2[j] = __builtin_amdgcn_mfma_f32_32x32x16_fp8_fp8(
              bb2[j][0], fa[0], acc2[j], 0, 0, 0);
          acc2[j] = __builtin_amdgcn_mfma_f32_32x32x16_fp8_fp8(
              bb2[j][1], fa[1], acc2[j], 0, 0, 0);
        }
      }
    __builtin_amdgcn_s_setprio(0);
    sbar();  // all waves done reading Bw2 + Ff
    if (nb < 7) STAGE_W2F(nb + 1);  // overlaps next GEMM1 + swish
  }
#undef STAGE_W1F
#undef STAGE_W2F
  // ---- epilogue: out = acc2 + b2 + xw (register residual) ----
#pragma unroll
  for (int j = 0; j < 2; ++j) {
#pragma unroll
    for (int q = 0; q < 4; ++q) {
      int n = fq * 64 + j * 32 + q * 8 + h * 4;
      size_t off = (size_t)m * 256 + n;
      const float4 bv = *reinterpret_cast<const float4*>(&b2[n]);
      float4 o;
      o.x = acc2[j][q * 4 + 0] + bv.x + xw[j][q * 4 + 0];
      o.y = acc2[j][q * 4 + 1] + bv.y + xw[j][q * 4 + 1];
      o.z = acc2[j][q * 4 + 2] + bv.z + xw[j][q * 4 + 2];
      o.w = acc2[j][q * 4 + 3] + bv.w + xw[j][q * 4 + 3];
      *reinterpret_cast<float4*>(&outp[off]) = o;
    }
  }
}

// ---------------- attention v9: head-major in AND out -----------------------
__global__ __launch_bounds__(256) void attn_kernel(const u8* __restrict__ kq8,
                                                   const u16* __restrict__ v16,
                                                   u8* __restrict__ o8) {
  __shared__ u8 q8[256 * 48];       // 12KB (rows stride 48B)
  __shared__ u16 vT[32 * 256];      // 16KB
  __shared__ u16 pT[4 * 16 * 64];   //  8KB (1 region per wave)
  int bh = blockIdx.x;
  int b = bh >> 3, h = bh & 7;
  int tid = threadIdx.x, wid = tid >> 6, lane = tid & 63;
  int l16 = lane & 15, lh = lane >> 4;
  const u8* kqh = kq8 + ((size_t)h * NT + (size_t)b * TT) * 64;
  const u16* vh = v16 + ((size_t)h * NT + (size_t)b * TT) * 32;
  u8* oh = o8 + ((size_t)h * NT + (size_t)b * TT) * 32;
  {
    int sr = tid >> 2, c = tid & 3;
    for (int s = sr; s < 256; s += 64) {
      // Q: 32B/row fp8 (2 chunks; c<2)
      if (c < 2) {
        uint4 qv = *reinterpret_cast<const uint4*>(
            &kqh[(size_t)s * 64 + 32 + c * 16]);
        *reinterpret_cast<uint4*>(&q8[s * 48 + c * 16]) = qv;
      }
      // V: 64B/row bf16 (4 chunks), transposed into vT
      u16 tmp[8];
      *reinterpret_cast<uint4*>(tmp) = *reinterpret_cast<const uint4*>(
          &vh[(size_t)s * 32 + c * 8]);
#pragma unroll
      for (int e = 0; e < 8; ++e) {
        int d = c * 8 + e;
        vT[d * 256 + (((s >> 3) ^ ((d >> 1) & 7)) << 3) + (s & 7)] = tmp[e];
      }
    }
  }
  __syncthreads();
  u16* pw = &pT[wid * 16 * 64];
  const float C1 = 0.09016844f;  // SCALE * log2(e)
#pragma unroll
  for (int pp = 0; pp < 2; ++pp) {
    const int jA = 2 * pp, jB = 2 * pp + 1;
    int tA16 = (jA * 4 + wid) * 16, tB16 = (jB * 4 + wid) * 16;
    long kbA = *reinterpret_cast<const long*>(
        &kqh[(size_t)(tA16 + l16) * 64 + lh * 8]);
    long kbB = *reinterpret_cast<const long*>(
        &kqh[(size_t)(tB16 + l16) * 64 + lh * 8]);
    float m2A = -3e38f, m2B = -3e38f, lsA = 0.f, lsB = 0.f;
    f32x4 oA[2] = {}, oB[2] = {};
#pragma unroll
    for (int st = 0; st <= jB; ++st) {
      const bool actA = (st <= jA);  // compile-time after unroll
      int s0 = st << 6;
      float vA[4][4], vB[4][4], pmA[4], pmB[4];
#pragma unroll
      for (int sj = 0; sj < 4; ++sj) {
        int srow = s0 + sj * 16 + l16;
        long qa = *reinterpret_cast<const long*>(&q8[srow * 48 + lh * 8]);
        f32x4 z = {0.f, 0.f, 0.f, 0.f};
        f32x4 scB = __builtin_amdgcn_mfma_f32_16x16x32_fp8_fp8(qa, kbB, z, 0, 0, 0);
#pragma unroll
        for (int r = 0; r < 4; ++r) {
          float vb_ = scB[r];
          if (st == jB) {
            if (sj * 16 + lh * 4 + r > wid * 16 + l16) vb_ = -3e38f;
          }
          vB[sj][r] = vb_;
        }
        pmB[sj] = fmaxf(fmaxf(vB[sj][0], vB[sj][1]), fmaxf(vB[sj][2], vB[sj][3]));
        if (actA) {
          f32x4 scA = __builtin_amdgcn_mfma_f32_16x16x32_fp8_fp8(qa, kbA, z, 0, 0, 0);
#pragma unroll
          for (int r = 0; r < 4; ++r) {
            float va_ = scA[r];
            if (st == jA) {
              if (sj * 16 + lh * 4 + r > wid * 16 + l16) va_ = -3e38f;
            }
            vA[sj][r] = va_;
          }
          pmA[sj] = fmaxf(fmaxf(vA[sj][0], vA[sj][1]), fmaxf(vA[sj][2], vA[sj][3]));
        }
      }
      // ---- chain A: softmax -> pw -> PV-A ----
      if (actA) {
        float mx = fmaxf(fmaxf(pmA[0], pmA[1]), fmaxf(pmA[2], pmA[3]));
        mx = fmaxf(mx, __shfl_xor(mx, 16, 64));
        mx = fmaxf(mx, __shfl_xor(mx, 32, 64));
        float mxs = mx * C1;
        if (!__all(mxs <= m2A + 8.0f)) {
          float mn = fmaxf(m2A, mxs);
          float alpha = exp2f(m2A - mn);
          m2A = mn;
          lsA *= alpha;
#pragma unroll
          for (int r = 0; r < 4; ++r) {
            float a = __shfl(alpha, (lane & 48) | (lh * 4 + r), 64);
            oA[0][r] *= a;
            oA[1][r] *= a;
          }
        }
#pragma unroll
        for (int sj = 0; sj < 4; ++sj) {
          float p0 = exp2f(__builtin_fmaf(vA[sj][0], C1, -m2A));
          float p1 = exp2f(__builtin_fmaf(vA[sj][1], C1, -m2A));
          float p2 = exp2f(__builtin_fmaf(vA[sj][2], C1, -m2A));
          float p3 = exp2f(__builtin_fmaf(vA[sj][3], C1, -m2A));
          lsA += (p0 + p1) + (p2 + p3);
          uint2 pkv = f2bfx4(p0, p1, p2, p3);
          *reinterpret_cast<uint2*>(
              (char*)pw + ((l16 * 128 + sj * 32 + lh * 8) ^ ((l16 & 7) << 4))) = pkv;
        }
#pragma unroll
        for (int ks = 0; ks < 2; ++ks) {
          bf16x8 pa = *reinterpret_cast<const bf16x8*>(
              (char*)pw + ((l16 * 128 + ks * 64 + lh * 16) ^ ((l16 & 7) << 4)));
#pragma unroll
          for (int nI = 0; nI < 2; ++nI) {
            int d = nI * 16 + l16;
            int sch = ((s0 + ks * 32 + lh * 8) >> 3) ^ ((d >> 1) & 7);
            bf16x8 vb = *reinterpret_cast<const bf16x8*>(&vT[d * 256 + (sch << 3)]);
            oA[nI] = __builtin_amdgcn_mfma_f32_16x16x32_bf16(pa, vb, oA[nI], 0, 0, 0);
          }
        }
      }
      // ---- chain B: softmax -> pw (reuse; wave-private, DS in-order) -> PV-B
      {
        float mx = fmaxf(fmaxf(pmB[0], pmB[1]), fmaxf(pmB[2], pmB[3]));
        mx = fmaxf(mx, __shfl_xor(mx, 16, 64));
        mx = fmaxf(mx, __shfl_xor(mx, 32, 64));
        float mxs = mx * C1;
        if (!__all(mxs <= m2B + 8.0f)) {
          float mn = fmaxf(m2B, mxs);
          float alpha = exp2f(m2B - mn);
          m2B = mn;
          lsB *= alpha;
#pragma unroll
          for (int r = 0; r < 4; ++r) {
            float a = __shfl(alpha, (lane & 48) | (lh * 4 + r), 64);
            oB[0][r] *= a;
            oB[1][r] *= a;
          }
        }
#pragma unroll
        for (int sj = 0; sj < 4; ++sj) {
          float p0 = exp2f(__builtin_fmaf(vB[sj][0], C1, -m2B));
          float p1 = exp2f(__builtin_fmaf(vB[sj][1], C1, -m2B));
          float p2 = exp2f(__builtin_fmaf(vB[sj][2], C1, -m2B));
          float p3 = exp2f(__builtin_fmaf(vB[sj][3], C1, -m2B));
          lsB += (p0 + p1) + (p2 + p3);
          uint2 pkv = f2bfx4(p0, p1, p2, p3);
          *reinterpret_cast<uint2*>(
              (char*)pw + ((l16 * 128 + sj * 32 + lh * 8) ^ ((l16 & 7) << 4))) = pkv;
        }
#pragma unroll
        for (int ks = 0; ks < 2; ++ks) {
          bf16x8 pa = *reinterpret_cast<const bf16x8*>(
              (char*)pw + ((l16 * 128 + ks * 64 + lh * 16) ^ ((l16 & 7) << 4)));
#pragma unroll
          for (int nI = 0; nI < 2; ++nI) {
            int d = nI * 16 + l16;
            int sch = ((s0 + ks * 32 + lh * 8) >> 3) ^ ((d >> 1) & 7);
            bf16x8 vb = *reinterpret_cast<const bf16x8*>(&vT[d * 256 + (sch << 3)]);
            oB[nI] = __builtin_amdgcn_mfma_f32_16x16x32_bf16(pa, vb, oB[nI], 0, 0, 0);
          }
        }
      }
    }
    // ---- reduce + output both chains (head-major o8h) ----
    lsA += __shfl_xor(lsA, 16, 64);
    lsA += __shfl_xor(lsA, 32, 64);
    lsB += __shfl_xor(lsB, 16, 64);
    lsB += __shfl_xor(lsB, 32, 64);
    int obyte = (l16 >> 3) * 16 + (l16 & 7);
#pragma unroll
    for (int r = 0; r < 4; ++r) {
      float laA = __shfl(lsA, (lane & 48) | (lh * 4 + r), 64);
      float laB = __shfl(lsB, (lane & 48) | (lh * 4 + r), 64);
      float invA = 1.0f / laA, invB = 1.0f / laB;
      int tA = tA16 + lh * 4 + r, tB = tB16 + lh * 4 + r;
#pragma unroll
      for (int nI = 0; nI < 2; ++nI) {
        oh[(size_t)tA * 32 + obyte + nI * 8] = f2f8(oA[nI][r] * invA);
        oh[(size_t)tB * 32 + obyte + nI * 8] = f2f8(oB[nI][r] * invB);
      }
    }
  }
}

// ---------------- launch ----------------------------------------------------
extern "C" void kernel_launch(void* const* d_in, const int* in_sizes, int n_in,
                              void* d_out, int out_size, void* d_ws, size_t ws_size,
                              hipStream_t stream) {
  const float* x   = (const float*)d_in[0];
  const float* Wk  = (const float*)d_in[1];
  const float* Wq  = (const float*)d_in[2];
  const float* Wv  = (const float*)d_in[3];
  const float* Wp  = (const float*)d_in[4];
  const float* bp  = (const float*)d_in[5];
  const float* W1  = (const float*)d_in[6];
  const float* b1  = (const float*)d_in[7];
  const float* W2  = (const float*)d_in[8];
  const float* b2  = (const float*)d_in[9];
  const float* g1  = (const float*)d_in[10];
  const float* be1 = (const float*)d_in[11];
  const float* g2  = (const float*)d_in[12];
  const float* be2 = (const float*)d_in[13];

  char* ws = (char*)d_ws;
  u8*  kq8 = (u8*)(ws + 0);                   // [H][NT][64] fp8 K|Q head-major (16MB)
  u16* v16 = (u16*)(ws + 16777216);           // [H][NT][32] bf16 V head-major (16MB)
  u8*  o8  = (u8*)(ws + 50331648);            // [H][NT][32] fp8 head-major (8MB)
  u8*  hb  = (u8*)(ws + 100663296);           // [NT][256] fp8: LN1 out, then LN2 out
  char* wb = ws + 117440512;
  u8*  WkqvT8 = (u8*)(wb);                    // 192KB
  u8*  WpT8   = (u8*)(wb + 196608);           // 64KB
  u8*  W1T8   = (u8*)(wb + 196608 + 65536);   // 256KB
  u8*  W2T8   = (u8*)(wb + 196608 + 65536 + 262144);  // 256KB

  // fused: weight conversion (blocks 0..191) + LN1 (blocks 192..8383)
  conv_ln<<<192 + NT / 4, 256, 0, stream>>>(Wk, Wq, Wv, Wp, W1, W2,
                                            WkqvT8, WpT8, W1T8, W2T8,
                                            x, g1, be1, hb);
  qkv_fused<<<NT / 64, 512, 0, stream>>>(hb, WkqvT8, kq8, v16);
  attn_kernel<<<BB * HH, 256, 0, stream>>>(kq8, v16, o8);
  // FUSED: Wp + bias + residual + LN2 + FFN + final residual -> d_out
  wp_ffn<<<NT / 64, 512, 0, stream>>>(o8, WpT8, bp, x, W1T8, W2T8,
                                      b1, b2, g2, be2, hb, (float*)d_out);
}